// Round 4
// baseline (339.269 us; speedup 1.0000x reference)
//
#include <hip/hip_runtime.h>
#include <hip/hip_bf16.h>
#include <math.h>

typedef __bf16 bf16_t;
typedef bf16_t bf16x4 __attribute__((ext_vector_type(4)));
typedef bf16_t bf16x8 __attribute__((ext_vector_type(8)));
typedef float  f32x4  __attribute__((ext_vector_type(4)));

#define SEQ 200
#define DD  64
#define NT  13     // seq tiles of 16

#define MFMA(a, b, c) __builtin_amdgcn_mfma_f32_16x16x32_bf16((a), (b), (c), 0, 0, 0)

// ---------------- prep kernel: weight fragments (bf16, transposed) + Q ----------------
// Wbc[n][k] = W1b - W1c ; W1dt[n][k] = W1d ; W2t[n][k] = W2^T ; Q[b][n] = b1 + em@(W1a+W1c)
__global__ __launch_bounds__(256) void prep_kernel(
    const float* __restrict__ em, const float* __restrict__ W1,
    const float* __restrict__ b1, const float* __restrict__ W2,
    bf16_t* __restrict__ Wbc, bf16_t* __restrict__ W1dt,
    bf16_t* __restrict__ W2t, float* __restrict__ Q)
{
  const int tid = threadIdx.x;
  if (blockIdx.x == 0) {
    for (int i = tid; i < 64 * 64; i += 256) {
      int n = i >> 6, k = i & 63;
      Wbc[i]  = (bf16_t)(W1[(64 + k) * 64 + n] - W1[(128 + k) * 64 + n]);
      W1dt[i] = (bf16_t)(W1[(192 + k) * 64 + n]);
    }
    for (int i = tid; i < 32 * 64; i += 256) {
      int n = i >> 6, k = i & 63;
      W2t[i] = (bf16_t)(W2[k * 32 + n]);
    }
  } else {
    int b = (blockIdx.x - 1) * 4 + (tid >> 6);
    int n = tid & 63;
    float acc = b1[n];
    for (int d = 0; d < 64; ++d)
      acc += em[(size_t)b * 64 + d] * (W1[d * 64 + n] + W1[(128 + d) * 64 + n]);
    Q[(size_t)b * 64 + n] = acc;
  }
}

// ---------------- main kernel: ONE WAVE per batch row, no block barriers ----------------
// Per-wave LDS region (4416 B): h1 scratch [16][72] bf16 (2304 B) overlaid by
// pool [16][68] f32 (4352 B); lam [16] f32 at +4352. Same-wave DS ordering only.
__global__ __launch_bounds__(256, 4) void din_kernel(
    const float* __restrict__ em, const float* __restrict__ eu,
    const float* __restrict__ Xu, const float* __restrict__ b2,
    const float* __restrict__ W3, const float* __restrict__ gam,
    const float* __restrict__ bet, const float* __restrict__ mmean,
    const float* __restrict__ mvar, const bf16_t* __restrict__ Wbc,
    const bf16_t* __restrict__ W1dt, const bf16_t* __restrict__ W2t,
    const float* __restrict__ Q, float* __restrict__ out)
{
  __shared__ __align__(16) unsigned char lds[4 * 4416];

  const int tid  = threadIdx.x;
  const int wid  = tid >> 6;
  const int lane = tid & 63;
  const int g    = lane >> 4;
  const int l16  = lane & 15;
  const int b    = blockIdx.x * 4 + wid;

  bf16_t* h1   = (bf16_t*)(lds + wid * 4416);          // [16][72] bf16
  float*  pool = (float*)(lds + wid * 4416);           // [16][68] f32 (overlay)
  float*  lam  = (float*)(lds + wid * 4416 + 4352);    // [16] f32

  const bf16x8* Wbc8  = (const bf16x8*)Wbc;
  const bf16x8* W1dt8 = (const bf16x8*)W1dt;
  const bf16x8* W2t8  = (const bf16x8*)W2t;

  // ---- wave-invariant fragments (all L1/L2-hot) ----
  float eml[2][8];
  #pragma unroll
  for (int c = 0; c < 2; ++c) {
    float4 e0 = *(const float4*)&em[(size_t)b * DD + 32 * c + 8 * g];
    float4 e1 = *(const float4*)&em[(size_t)b * DD + 32 * c + 8 * g + 4];
    eml[c][0] = e0.x; eml[c][1] = e0.y; eml[c][2] = e0.z; eml[c][3] = e0.w;
    eml[c][4] = e1.x; eml[c][5] = e1.y; eml[c][6] = e1.z; eml[c][7] = e1.w;
  }
  // B' = (W1b - W1c) + diag(em) * W1d, fragments for all 4 n-tiles
  bf16x8 bB[4][2];
  #pragma unroll
  for (int nt = 0; nt < 4; ++nt) {
    int n = nt * 16 + l16;
    #pragma unroll
    for (int c = 0; c < 2; ++c) {
      bf16x8 wbc = Wbc8[n * 8 + 4 * c + g];
      bf16x8 w1d = W1dt8[n * 8 + 4 * c + g];
      #pragma unroll
      for (int j = 0; j < 8; ++j)
        bB[nt][c][j] = (bf16_t)((float)wbc[j] + eml[c][j] * (float)w1d[j]);
    }
  }
  bf16x8 bW2[2][2];
  #pragma unroll
  for (int c = 0; c < 2; ++c)
    #pragma unroll
    for (int u = 0; u < 2; ++u)
      bW2[c][u] = W2t8[(16 * u + l16) * 8 + 4 * c + g];

  float qv[4];
  #pragma unroll
  for (int nt = 0; nt < 4; ++nt) qv[nt] = Q[(size_t)b * DD + nt * 16 + l16];
  const float b2v0 = b2[l16], b2v1 = b2[16 + l16];
  const float w3v0 = W3[l16], w3v1 = W3[16 + l16];

  // ---- online softmax state ----
  float m = -INFINITY, l = 0.f;
  float pacc[2][8];
  #pragma unroll
  for (int c = 0; c < 2; ++c)
    #pragma unroll
    for (int j = 0; j < 8; ++j) pacc[c][j] = 0.f;

  const float* Xbase = Xu + (size_t)b * SEQ * DD;

  for (int t = 0; t < NT; ++t) {
    const int s = 16 * t + l16;
    // A-fragments direct from global (f32 -> bf16), masked pad rows
    bf16x8 xf[2];
    if (s < SEQ) {
      const float* Xr = Xbase + (size_t)s * DD;
      #pragma unroll
      for (int c = 0; c < 2; ++c) {
        float4 x0 = *(const float4*)&Xr[32 * c + 8 * g];
        float4 x1 = *(const float4*)&Xr[32 * c + 8 * g + 4];
        xf[c][0] = (bf16_t)x0.x; xf[c][1] = (bf16_t)x0.y;
        xf[c][2] = (bf16_t)x0.z; xf[c][3] = (bf16_t)x0.w;
        xf[c][4] = (bf16_t)x1.x; xf[c][5] = (bf16_t)x1.y;
        xf[c][6] = (bf16_t)x1.z; xf[c][7] = (bf16_t)x1.w;
      }
    } else {
      #pragma unroll
      for (int c = 0; c < 2; ++c)
        #pragma unroll
        for (int j = 0; j < 8; ++j) xf[c][j] = (bf16_t)0.f;
    }

    // stage 1: h1_pre = Xu_tile @ B' (+Q), all 4 n-tiles
    f32x4 a1[4];
    #pragma unroll
    for (int nt = 0; nt < 4; ++nt) {
      f32x4 a = {0.f, 0.f, 0.f, 0.f};
      a = MFMA(xf[0], bB[nt][0], a);
      a = MFMA(xf[1], bB[nt][1], a);
      a1[nt] = a;
    }
    // h1 = relu -> LDS transpose (C-layout row = 4g+r, col = nt*16+l16)
    #pragma unroll
    for (int nt = 0; nt < 4; ++nt)
      #pragma unroll
      for (int r = 0; r < 4; ++r) {
        float v = a1[nt][r] + qv[nt];
        v = v > 0.f ? v : 0.f;
        h1[(4 * g + r) * 72 + nt * 16 + l16] = (bf16_t)v;
      }

    // stage 2: P = h1 @ W2 (K=64, N=32)
    bf16x8 h0 = *(const bf16x8*)&h1[l16 * 72 + 8 * g];
    bf16x8 h1f = *(const bf16x8*)&h1[l16 * 72 + 32 + 8 * g];
    f32x4 a20 = {0.f, 0.f, 0.f, 0.f}, a21 = {0.f, 0.f, 0.f, 0.f};
    a20 = MFMA(h0, bW2[0][0], a20);
    a20 = MFMA(h1f, bW2[1][0], a20);
    a21 = MFMA(h0, bW2[0][1], a21);
    a21 = MFMA(h1f, bW2[1][1], a21);

    // stage 3: logits for the 16 rows of this tile
    #pragma unroll
    for (int r = 0; r < 4; ++r) {
      float p0 = fmaxf(a20[r] + b2v0, 0.f) * w3v0;
      float p1 = fmaxf(a21[r] + b2v1, 0.f) * w3v1;
      float pr = p0 + p1;
      pr += __shfl_xor(pr, 1);
      pr += __shfl_xor(pr, 2);
      pr += __shfl_xor(pr, 4);
      pr += __shfl_xor(pr, 8);
      if (l16 == 0) {
        int row = 4 * g + r;
        lam[row] = (16 * t + row < SEQ) ? pr : -INFINITY;
      }
    }
    float lv = lam[l16];                    // row l16's logit (same-wave DS order)
    float mt = lv;
    mt = fmaxf(mt, __shfl_xor(mt, 1));
    mt = fmaxf(mt, __shfl_xor(mt, 2));
    mt = fmaxf(mt, __shfl_xor(mt, 4));
    mt = fmaxf(mt, __shfl_xor(mt, 8));

    // online-softmax update
    float mn = fmaxf(m, mt);
    float alpha = __expf(m - mn);           // first iter: exp(-inf) = 0
    float e = __expf(lv - mn);              // masked rows: exp(-inf) = 0
    float es = e;
    es += __shfl_xor(es, 1);
    es += __shfl_xor(es, 2);
    es += __shfl_xor(es, 4);
    es += __shfl_xor(es, 8);
    l = l * alpha + es;
    #pragma unroll
    for (int c = 0; c < 2; ++c)
      #pragma unroll
      for (int j = 0; j < 8; ++j)
        pacc[c][j] = pacc[c][j] * alpha + e * (float)xf[c][j];
    m = mn;
  }

  // ---- reduce pacc over the 16 row-lanes via per-wave LDS (overlays h1) ----
  {
    f32x4 p;
    p[0] = pacc[0][0]; p[1] = pacc[0][1]; p[2] = pacc[0][2]; p[3] = pacc[0][3];
    *(f32x4*)&pool[l16 * 68 + 8 * g] = p;
    p[0] = pacc[0][4]; p[1] = pacc[0][5]; p[2] = pacc[0][6]; p[3] = pacc[0][7];
    *(f32x4*)&pool[l16 * 68 + 8 * g + 4] = p;
    p[0] = pacc[1][0]; p[1] = pacc[1][1]; p[2] = pacc[1][2]; p[3] = pacc[1][3];
    *(f32x4*)&pool[l16 * 68 + 32 + 8 * g] = p;
    p[0] = pacc[1][4]; p[1] = pacc[1][5]; p[2] = pacc[1][6]; p[3] = pacc[1][7];
    *(f32x4*)&pool[l16 * 68 + 32 + 8 * g + 4] = p;
  }
  float ps = 0.f;
  #pragma unroll
  for (int r = 0; r < 16; ++r) ps += pool[r * 68 + lane];
  const float pooled = ps * (1.f / l);

  // ---- BN + concat output (lane = feature dim) ----
  const size_t ob = (size_t)b * 192;
  out[ob + lane] =
      (pooled - mmean[lane]) * rsqrtf(mvar[lane] + 1e-3f) * gam[lane] + bet[lane];
  float emv = em[(size_t)b * DD + lane];
  out[ob + 64 + lane] =
      (emv - mmean[64 + lane]) * rsqrtf(mvar[64 + lane] + 1e-3f) * gam[64 + lane] +
      bet[64 + lane];
  out[ob + 128 + lane] = eu[(size_t)b * DD + lane];
}

extern "C" void kernel_launch(void* const* d_in, const int* in_sizes, int n_in,
                              void* d_out, int out_size, void* d_ws, size_t ws_size,
                              hipStream_t stream) {
  const float* em = (const float*)d_in[0];
  const float* eu = (const float*)d_in[1];
  const float* Xu = (const float*)d_in[2];
  const float* W1 = (const float*)d_in[3];
  const float* b1 = (const float*)d_in[4];
  const float* W2 = (const float*)d_in[5];
  const float* b2 = (const float*)d_in[6];
  const float* W3 = (const float*)d_in[7];
  // b3 dropped: constant logit shift is softmax-invariant
  const float* ga = (const float*)d_in[9];
  const float* be = (const float*)d_in[10];
  const float* mm = (const float*)d_in[11];
  const float* mv = (const float*)d_in[12];
  int B = in_sizes[0] / DD;

  float*  Q    = (float*)d_ws;
  bf16_t* Wbc  = (bf16_t*)((char*)d_ws + (size_t)B * 64 * 4);
  bf16_t* W1dt = Wbc  + 64 * 64;
  bf16_t* W2t  = W1dt + 64 * 64;

  prep_kernel<<<1 + B / 4, 256, 0, stream>>>(em, W1, b1, W2, Wbc, W1dt, W2t, Q);
  din_kernel<<<B / 4, 256, 0, stream>>>(em, eu, Xu, b2, W3, ga, be, mm, mv,
                                        Wbc, W1dt, W2t, Q, (float*)d_out);
}